// Round 4
// baseline (448.399 us; speedup 1.0000x reference)
//
#include <hip/hip_runtime.h>
#include <math.h>

#define BATCH 2048
#define NN 64
#define FEAT 40
#define M 10
#define WAVES 10
#define BLOCK (WAVES * 64)
#define PDS 65  // padded row stride for pd matrix (2-way bank alias only -> free)

// broadcast value from lane `l` (compile-time const after unroll) to all lanes
__device__ __forceinline__ float bl(float v, int l) {
    return __int_as_float(__builtin_amdgcn_readlane(__float_as_int(v), l));
}

// full 64-lane butterfly sum
__device__ __forceinline__ float wsum(float v) {
#pragma unroll
    for (int o = 32; o >= 1; o >>= 1) v += __shfl_xor(v, o, 64);
    return v;
}

// waves_per_eu(3,3): pin the backend's occupancy TARGET to 3 waves/EU ->
// register budget 512/3 ~ 170. This is the lever that stops the allocator
// from splitting A[64] into AGPRs (R1/R2: 40 arch VGPR + ~56 AGPR with
// v_accvgpr shuttles = ~2.4x VALU inflation). 10-wave blocks place as
// 3/3/2/2 waves per SIMD, so <=170 regs stays launchable (3x170 <= 512).
// NOTE: do NOT clobber AGPRs to force this (R3: agpr_count=256 -> block
// needs 3x296 regs on one SIMD -> unlaunchable -> abort).
__global__ __launch_bounds__(BLOCK)
__attribute__((amdgpu_waves_per_eu(3, 3)))
void muygps_kernel(
    const float* __restrict__ x,      // (20000, 40)
    const float* __restrict__ ls,     // (10,)
    const float* __restrict__ epsv,   // (10,)
    const int*   __restrict__ bidx,   // (2048,)
    const int*   __restrict__ nidx,   // (2048, 64)
    const float* __restrict__ tgt,    // (2048, 64, 10)
    float* __restrict__ out)          // pred(2048,10) | var(2048,10) | sigma(10)
{
    __shared__ float xnT[FEAT][NN];   // transposed neighbor features
    __shared__ float xbs[FEAT];       // batch-point features
    __shared__ float pds[NN * PDS];   // pairwise l2 distances (sqrt'ed)
    __shared__ float cds[NN];         // crosswise l2 distances

    const int b    = blockIdx.x;
    const int t    = threadIdx.x;
    const int w    = t >> 6;          // wave id 0..9
    const int lane = t & 63;

    // ---- phase 1: gather x rows into LDS (transposed) ----
    if (t < FEAT) xbs[t] = x[(long)bidx[b] * FEAT + t];
    for (int flat = t; flat < NN * FEAT; flat += BLOCK) {
        int n = flat & 63;       // consecutive threads -> consecutive n: conflict-free
        int f = flat >> 6;
        xnT[f][n] = x[(long)nidx[b * NN + n] * FEAT + f];
    }
    __syncthreads();

    // ---- phase 2: distance rows (64 pd rows + 1 cd row), striped over waves ----
    for (int r = w; r < NN + 1; r += WAVES) {
        float d2 = 0.f;
        if (r < NN) {
#pragma unroll
            for (int f = 0; f < FEAT; ++f) {
                float diff = xnT[f][r] - xnT[f][lane];
                d2 = fmaf(diff, diff, d2);
            }
            pds[r * PDS + lane] = sqrtf(d2);   // r==lane gives exactly 0
        } else {
#pragma unroll
            for (int f = 0; f < FEAT; ++f) {
                float diff = xbs[f] - xnT[f][lane];
                d2 = fmaf(diff, diff, d2);
            }
            cds[lane] = sqrtf(d2);
        }
    }
    __syncthreads();

    // ---- phase 3: wave w == model m; row-per-lane in-register Cholesky ----
    const int m = w;
    const float il = -1.0f / ls[m];
    const float ep = epsv[m];

    float A[NN];  // row `lane` of Kp, kept in arch VGPRs
    {
        const float* prow = &pds[lane * PDS];
#pragma unroll
        for (int j = 0; j < NN; ++j) {
            float v = __expf(prow[j] * il);
            A[j] = (j == lane) ? (v + ep) : v;
        }
    }

    // right-looking Cholesky; after step k, register k of lane i (i>=k) holds L[i][k]
    float invd = 0.f;  // lane k keeps 1/L[k][k]
#pragma unroll
    for (int k = 0; k < NN; ++k) {
        float akk = bl(A[k], k);
        float id  = rsqrtf(akk);
        A[k] *= id;                       // column k of L (distributed over lanes)
        if (lane == k) invd = id;
#pragma unroll
        for (int j = k + 1; j < NN; ++j) {
            float cj = bl(A[k], j);       // L[j][k]
            A[j] = fmaf(-A[k], cj, A[j]); // A[i][j] -= L[i][k]*L[j][k]
        }
    }

    // ---- two forward solves: w1 = L^-1 Y_m, w2 = L^-1 Kcross_m ----
    float Kc = __expf(cds[lane] * il);
    float yv = tgt[(b * NN + lane) * M + m];

    float b1 = yv, b2 = Kc;
    float w1 = 0.f, w2 = 0.f;
#pragma unroll
    for (int k = 0; k < NN; ++k) {
        float ik = bl(invd, k);
        float t1 = bl(b1, k) * ik;
        float t2 = bl(b2, k) * ik;
        if (lane == k) { w1 = t1; w2 = t2; }
        b1 = fmaf(-A[k], t1, b1);
        b2 = fmaf(-A[k], t2, b2);
    }

    // ---- outputs: quadratic forms, no backward solves needed ----
    float pred = wsum(w1 * w2);          // Kc^T Kp^-1 Y
    float quad = wsum(w2 * w2);          // Kc^T Kp^-1 Kc
    float sig  = wsum(w1 * w1);          // Y^T Kp^-1 Y
    if (lane == 0) {
        out[b * M + m] = pred;
        out[BATCH * M + b * M + m] = 1.0f - quad;
        atomicAdd(&out[2 * BATCH * M + m], sig * (1.0f / (float)(BATCH * NN)));
    }
}

extern "C" void kernel_launch(void* const* d_in, const int* in_sizes, int n_in,
                              void* d_out, int out_size, void* d_ws, size_t ws_size,
                              hipStream_t stream) {
    const float* x   = (const float*)d_in[0];
    const float* ls  = (const float*)d_in[1];
    const float* ep  = (const float*)d_in[2];
    const int*   bi  = (const int*)d_in[3];
    const int*   ni  = (const int*)d_in[4];
    const float* tg  = (const float*)d_in[5];
    float* out = (float*)d_out;

    // sigma_sq region is accumulated via atomics; d_out is poisoned each launch
    hipMemsetAsync(out + 2 * BATCH * M, 0, M * sizeof(float), stream);
    muygps_kernel<<<BATCH, BLOCK, 0, stream>>>(x, ls, ep, bi, ni, tg, out);
}

// Round 5
// 407.108 us; speedup vs baseline: 1.1014x; 1.1014x over previous
//
#include <hip/hip_runtime.h>
#include <math.h>

#define BATCH 2048
#define NN 64
#define FEAT 40
#define M 10
#define WAVES 10
#define BLOCK (WAVES * 64)
#define PDS 65  // padded row stride for pd matrix (2-way bank alias only -> free)

// Force all 64 A[] values to be simultaneously resident in ARCH VGPRs at this
// point. "+v" is the arch-VGPR constraint; an AGPR home would require copies
// around every fence, so the allocator keeps arch homes (copy-free). This is
// the correct form of R3's failed AGPR-clobber (which inflated agpr_count to
// 256 and made the block unlaunchable). R1-R4 evidence: allocator homes A[] in
// AGPRs (VGPR_Count 40/68 < 100 needed) and pays v_accvgpr_read/write copies
// -> measured ~2.3x dynamic-VALU inflation (issue time 227-235us vs ~100us
// ideal), identical across occupancy settings.
#define FENCE_A() asm volatile("" : \
  "+v"(A[0]),"+v"(A[1]),"+v"(A[2]),"+v"(A[3]),"+v"(A[4]),"+v"(A[5]),"+v"(A[6]),"+v"(A[7]), \
  "+v"(A[8]),"+v"(A[9]),"+v"(A[10]),"+v"(A[11]),"+v"(A[12]),"+v"(A[13]),"+v"(A[14]),"+v"(A[15]), \
  "+v"(A[16]),"+v"(A[17]),"+v"(A[18]),"+v"(A[19]),"+v"(A[20]),"+v"(A[21]),"+v"(A[22]),"+v"(A[23]), \
  "+v"(A[24]),"+v"(A[25]),"+v"(A[26]),"+v"(A[27]),"+v"(A[28]),"+v"(A[29]),"+v"(A[30]),"+v"(A[31]), \
  "+v"(A[32]),"+v"(A[33]),"+v"(A[34]),"+v"(A[35]),"+v"(A[36]),"+v"(A[37]),"+v"(A[38]),"+v"(A[39]), \
  "+v"(A[40]),"+v"(A[41]),"+v"(A[42]),"+v"(A[43]),"+v"(A[44]),"+v"(A[45]),"+v"(A[46]),"+v"(A[47]), \
  "+v"(A[48]),"+v"(A[49]),"+v"(A[50]),"+v"(A[51]),"+v"(A[52]),"+v"(A[53]),"+v"(A[54]),"+v"(A[55]), \
  "+v"(A[56]),"+v"(A[57]),"+v"(A[58]),"+v"(A[59]),"+v"(A[60]),"+v"(A[61]),"+v"(A[62]),"+v"(A[63]))

// broadcast value from lane `l` (compile-time const after unroll) to all lanes
__device__ __forceinline__ float bl(float v, int l) {
    return __int_as_float(__builtin_amdgcn_readlane(__float_as_int(v), l));
}

// full 64-lane butterfly sum
__device__ __forceinline__ float wsum(float v) {
#pragma unroll
    for (int o = 32; o >= 1; o >>= 1) v += __shfl_xor(v, o, 64);
    return v;
}

// waves_per_eu(3,3): register budget 512/3 ~ 170 arch VGPRs so the fenced
// A[64] + working set fits without spill. 10-wave blocks place 3/3/2/2.
__global__ __launch_bounds__(BLOCK)
__attribute__((amdgpu_waves_per_eu(3, 3)))
void muygps_kernel(
    const float* __restrict__ x,      // (20000, 40)
    const float* __restrict__ ls,     // (10,)
    const float* __restrict__ epsv,   // (10,)
    const int*   __restrict__ bidx,   // (2048,)
    const int*   __restrict__ nidx,   // (2048, 64)
    const float* __restrict__ tgt,    // (2048, 64, 10)
    float* __restrict__ out)          // pred(2048,10) | var(2048,10) | sigma(10)
{
    __shared__ float xnT[FEAT][NN];   // transposed neighbor features
    __shared__ float xbs[FEAT];       // batch-point features
    __shared__ float pds[NN * PDS];   // pairwise l2 distances (sqrt'ed)
    __shared__ float cds[NN];         // crosswise l2 distances

    const int b    = blockIdx.x;
    const int t    = threadIdx.x;
    const int w    = t >> 6;          // wave id 0..9
    const int lane = t & 63;

    // ---- phase 1: gather x rows into LDS (transposed) ----
    if (t < FEAT) xbs[t] = x[(long)bidx[b] * FEAT + t];
    for (int flat = t; flat < NN * FEAT; flat += BLOCK) {
        int n = flat & 63;       // consecutive threads -> consecutive n: conflict-free
        int f = flat >> 6;
        xnT[f][n] = x[(long)nidx[b * NN + n] * FEAT + f];
    }
    __syncthreads();

    // ---- phase 2: distance rows, striped over waves. Hoist this lane's own
    // feature column into registers once (removes ~220 ds_reads/wave). ----
    {
        float xcol[FEAT];
#pragma unroll
        for (int f = 0; f < FEAT; ++f) xcol[f] = xnT[f][lane];

        for (int r = w; r < NN + 1; r += WAVES) {
            float d2 = 0.f;
            if (r < NN) {
#pragma unroll
                for (int f = 0; f < FEAT; ++f) {
                    float diff = xnT[f][r] - xcol[f];   // xnT[f][r]: broadcast read
                    d2 = fmaf(diff, diff, d2);
                }
                pds[r * PDS + lane] = sqrtf(d2);   // r==lane gives exactly 0
            } else {
#pragma unroll
                for (int f = 0; f < FEAT; ++f) {
                    float diff = xbs[f] - xcol[f];
                    d2 = fmaf(diff, diff, d2);
                }
                cds[lane] = sqrtf(d2);
            }
        }
    }
    __syncthreads();

    // ---- phase 3: wave w == model m; row-per-lane in-register Cholesky ----
    const int m = w;
    const float il = -1.0f / ls[m];
    const float ep = epsv[m];

    float A[NN];  // row `lane` of Kp, pinned to arch VGPRs via FENCE_A
    {
        const float* prow = &pds[lane * PDS];
#pragma unroll
        for (int j = 0; j < NN; ++j) {
            float v = __expf(prow[j] * il);
            A[j] = (j == lane) ? (v + ep) : v;
        }
    }

    // right-looking Cholesky; after step k, register k of lane i (i>=k) holds L[i][k]
    float invd = 0.f;  // lane k keeps 1/L[k][k]
#pragma unroll
    for (int k = 0; k < NN; ++k) {
        FENCE_A();                        // arch-VGPR residency each step
        float akk = bl(A[k], k);
        float id  = rsqrtf(akk);
        A[k] *= id;                       // column k of L (distributed over lanes)
        if (lane == k) invd = id;
#pragma unroll
        for (int j = k + 1; j < NN; ++j) {
            float cj = bl(A[k], j);       // L[j][k]
            A[j] = fmaf(-A[k], cj, A[j]); // A[i][j] -= L[i][k]*L[j][k]
        }
    }
    FENCE_A();

    // ---- two forward solves: w1 = L^-1 Y_m, w2 = L^-1 Kcross_m ----
    float Kc = __expf(cds[lane] * il);
    float yv = tgt[(b * NN + lane) * M + m];

    float b1 = yv, b2 = Kc;
    float w1 = 0.f, w2 = 0.f;
#pragma unroll
    for (int k = 0; k < NN; ++k) {
        float ik = bl(invd, k);
        float t1 = bl(b1, k) * ik;
        float t2 = bl(b2, k) * ik;
        if (lane == k) { w1 = t1; w2 = t2; }
        b1 = fmaf(-A[k], t1, b1);
        b2 = fmaf(-A[k], t2, b2);
    }

    // ---- outputs: quadratic forms, no backward solves needed ----
    float pred = wsum(w1 * w2);          // Kc^T Kp^-1 Y
    float quad = wsum(w2 * w2);          // Kc^T Kp^-1 Kc
    float sig  = wsum(w1 * w1);          // Y^T Kp^-1 Y
    if (lane == 0) {
        out[b * M + m] = pred;
        out[BATCH * M + b * M + m] = 1.0f - quad;
        atomicAdd(&out[2 * BATCH * M + m], sig * (1.0f / (float)(BATCH * NN)));
    }
}

extern "C" void kernel_launch(void* const* d_in, const int* in_sizes, int n_in,
                              void* d_out, int out_size, void* d_ws, size_t ws_size,
                              hipStream_t stream) {
    const float* x   = (const float*)d_in[0];
    const float* ls  = (const float*)d_in[1];
    const float* ep  = (const float*)d_in[2];
    const int*   bi  = (const int*)d_in[3];
    const int*   ni  = (const int*)d_in[4];
    const float* tg  = (const float*)d_in[5];
    float* out = (float*)d_out;

    // sigma_sq region is accumulated via atomics; d_out is poisoned each launch
    hipMemsetAsync(out + 2 * BATCH * M, 0, M * sizeof(float), stream);
    muygps_kernel<<<BATCH, BLOCK, 0, stream>>>(x, ls, ep, bi, ni, tg, out);
}

// Round 6
// 378.441 us; speedup vs baseline: 1.1849x; 1.0758x over previous
//
#include <hip/hip_runtime.h>
#include <math.h>

#define BATCH 2048
#define NN 64
#define FEAT 40
#define M 10
#define XNS 44   // padded LDS feature-row stride (floats); 176B = 16B-aligned for b128

// broadcast lane l (compile-time const after unroll) to all lanes
__device__ __forceinline__ float bl(float v, int l) {
    return __int_as_float(__builtin_amdgcn_readlane(__float_as_int(v), l));
}
// 64-lane butterfly sum
__device__ __forceinline__ float wsum(float v) {
#pragma unroll
    for (int o = 32; o >= 1; o >>= 1) v += __shfl_xor(v, o, 64);
    return v;
}

// One wave per batch element. Key insight: the M=10 models share (ls,eps) in
// the actual inputs -> Kp and Kcross are identical across models; the while
// loop below factors ONCE per distinct (ls,eps) group and solves each member
// model's Y against the shared Cholesky factor. Fully general: mismatched
// params just trigger another (never-taken in bench) while iteration.
// waves_per_eu(2,2): 256-reg budget for peak pressure ~125 (xcol40+A64+y10).
__global__ __launch_bounds__(64)
__attribute__((amdgpu_waves_per_eu(2, 2)))
void muygps_kernel(
    const float* __restrict__ x,      // (20000, 40)
    const float* __restrict__ ls,     // (10,)
    const float* __restrict__ epsv,   // (10,)
    const int*   __restrict__ bidx,   // (2048,)
    const int*   __restrict__ nidx,   // (2048, 64)
    const float* __restrict__ tgt,    // (2048, 64, 10)
    float* __restrict__ out)          // pred(2048,10) | var(2048,10) | sigma(10)
{
    __shared__ float xn[NN * XNS];    // neighbor features, row-major padded
    __shared__ float xb[FEAT];        // batch-point features

    const int b    = blockIdx.x;
    const int lane = threadIdx.x;     // 0..63

    // ---- stage: this lane's neighbor row -> regs (xcol) AND LDS (for other lanes)
    const float* xrow = x + (long)nidx[b * NN + lane] * FEAT;
    float xcol[FEAT];
#pragma unroll
    for (int f = 0; f < FEAT; f += 4) {
        float4 v = *(const float4*)(xrow + f);
        xcol[f] = v.x; xcol[f+1] = v.y; xcol[f+2] = v.z; xcol[f+3] = v.w;
        *(float4*)(&xn[lane * XNS + f]) = v;
    }
    if (lane < FEAT / 4)
        *(float4*)(&xb[lane * 4]) = *(const float4*)(x + (long)bidx[b] * FEAT + lane * 4);

    // ---- preload this lane's targets for all models (static-indexed regs)
    const float* trow = tgt + ((long)b * NN + lane) * M;
    float y[M];
#pragma unroll
    for (int i = 0; i < M; i += 2) {
        float2 v = *(const float2*)(trow + i);   // 8B-aligned (stride 40B)
        y[i] = v.x; y[i + 1] = v.y;
    }

    __syncthreads();

    // ---- crosswise distance for this lane's neighbor (shared across models)
    float cd2 = 0.f;
#pragma unroll
    for (int f = 0; f < FEAT; ++f) {
        float d = xb[f] - xcol[f];
        cd2 = fmaf(d, d, cd2);
    }
    const float cd = sqrtf(cd2);

    // ---- group loop over distinct (ls,eps); executes ONCE for uniform params
    unsigned done = 0;
    const unsigned all = (1u << M) - 1u;
    while (done != all) {
        const int   lead = __ffs(~done) - 1;       // wave-uniform
        const float lls  = ls[lead];
        const float lep  = epsv[lead];
        const float il   = -1.0f / lls;

        // build row `lane` of Kp: fused distance + exp from LDS
        // (subtract-then-square: duplicate neighbor rows give EXACT d2=0,
        //  matching reference semantics -> sigma_sq stays accurate)
        float A[NN];
#pragma unroll
        for (int j = 0; j < NN; ++j) {
            const float* r = &xn[j * XNS];         // broadcast reads
            float d2 = 0.f;
#pragma unroll
            for (int f = 0; f < FEAT; ++f) {
                float d = r[f] - xcol[f];
                d2 = fmaf(d, d, d2);
            }
            float v = __expf(sqrtf(d2) * il);
            A[j] = (j == lane) ? (v + lep) : v;    // diag: exactly 1+eps
        }

        // right-looking Cholesky, row-per-lane; A[k] becomes column k of L
        float invd = 0.f;                          // lane k: 1/L[k][k]
#pragma unroll
        for (int k = 0; k < NN; ++k) {
            float akk = bl(A[k], k);
            float id  = rsqrtf(akk);
            A[k] *= id;
            if (lane == k) invd = id;
#pragma unroll
            for (int j = k + 1; j < NN; ++j) {
                float cj = bl(A[k], j);            // L[j][k]
                A[j] = fmaf(-A[k], cj, A[j]);
            }
        }

        // forward solve L w = rhs (w distributed: lane k holds w[k])
        auto fsolve = [&](float rhs) {
            float w = 0.f;
#pragma unroll
            for (int k = 0; k < NN; ++k) {
                float t = bl(rhs, k) * bl(invd, k);
                if (lane == k) w = t;
                rhs = fmaf(-A[k], t, rhs);
            }
            return w;
        };

        const float w2v  = fsolve(__expf(cd * il));   // L^-1 Kcross (shared)
        const float quad = wsum(w2v * w2v);           // Kc^T Kp^-1 Kc (shared)

#pragma unroll
        for (int m = 0; m < M; ++m) {
            if (done & (1u << m)) continue;                 // uniform
            if (ls[m] != lls || epsv[m] != lep) continue;   // uniform
            float w1v  = fsolve(y[m]);                      // L^-1 y_m
            float pred = wsum(w1v * w2v);
            float sig  = wsum(w1v * w1v);
            if (lane == 0) {
                out[b * M + m] = pred;
                out[BATCH * M + b * M + m] = 1.0f - quad;
                atomicAdd(&out[2 * BATCH * M + m], sig * (1.0f / (float)(BATCH * NN)));
            }
            done |= 1u << m;
        }
    }
}

extern "C" void kernel_launch(void* const* d_in, const int* in_sizes, int n_in,
                              void* d_out, int out_size, void* d_ws, size_t ws_size,
                              hipStream_t stream) {
    const float* x   = (const float*)d_in[0];
    const float* ls  = (const float*)d_in[1];
    const float* ep  = (const float*)d_in[2];
    const int*   bi  = (const int*)d_in[3];
    const int*   ni  = (const int*)d_in[4];
    const float* tg  = (const float*)d_in[5];
    float* out = (float*)d_out;

    // sigma_sq region accumulated via atomics; d_out is poisoned each launch
    hipMemsetAsync(out + 2 * BATCH * M, 0, M * sizeof(float), stream);
    muygps_kernel<<<BATCH, 64, 0, stream>>>(x, ls, ep, bi, ni, tg, out);
}